// Round 1
// baseline (595.518 us; speedup 1.0000x reference)
//
#include <hip/hip_runtime.h>

#define KK 32
#define KP 33
#define NMAXC 256
#define BCH 32            // bsz * ENS
#define NPADC 32768
#define TARGETC 32640
#define LBLK 128
#define MBLK 256          // NPADC / LBLK
#define GSZ 16
#define NG 16             // MBLK / GSZ
#define SS 2

#define OFFS(i) ((i)*255 - (i)*((i)-1)/2)

__device__ __forceinline__ double shfl_up1(double v) {
    return __shfl_up(v, 1, 64);
}

__device__ __forceinline__ void decode_ij(int t, int& oi, int& oj) {
    int ii = (int)((511.0 - sqrt(511.0 * 511.0 - 8.0 * (double)t)) * 0.5);
    if (ii < 0) ii = 0;
    if (ii > 254) ii = 254;
    while (ii < 254 && OFFS(ii + 1) <= t) ++ii;
    while (ii > 0 && OFFS(ii) > t) --ii;
    oi = ii;
    oj = t - OFFS(ii) + ii + 1;
}

// wave-level 33-point polynomial product: out[k] = sum_{j<=k} A[j]*B[k-j]
__device__ __forceinline__ double conv33(double a, double b) {
    int lane = threadIdx.x & 63;
    double s = 0.0;
    double brot = b;
    for (int j = 0; j <= KK; ++j) {
        double aj = __shfl(a, j, 64);
        s = fma((j <= lane) ? aj : 0.0, brot, s);
        brot = shfl_up1(brot);
    }
    return s;
}

// ---- kernel 1: x = exp(theta), theta = s_ij + s_ji for triu pairs, 0 for padding
__global__ void k_exp_theta(const float* __restrict__ sc, double* __restrict__ X) {
    int idx = blockIdx.x * blockDim.x + threadIdx.x;
    if (idx >= BCH * NPADC) return;
    int b = idx >> 15;
    int t = idx & (NPADC - 1);
    double x = 0.0;
    if (t < TARGETC) {
        int i, j;
        decode_ij(t, i, j);
        double th = (double)sc[(b * NMAXC + i) * NMAXC + j] + (double)sc[(b * NMAXC + j) * NMAXC + i];
        x = exp(th);
    }
    X[idx] = x;
}

// ---- kernel 2: per-block elementary symmetric polys (linear domain)
__global__ void k_block_poly(const double* __restrict__ X, double* __restrict__ Bp) {
    int lane = threadIdx.x;
    int task = blockIdx.x;                 // b*MBLK + m
    int b = task / MBLK, m = task % MBLK;
    const double* xb = X + (size_t)b * NPADC + (size_t)m * LBLK;
    double c = (lane == 0) ? 1.0 : 0.0;
    for (int j = 0; j < LBLK; ++j) {
        double xv = xb[j];
        double up = shfl_up1(c);
        if (lane == 0) up = 0.0;
        c = fma(xv, up, c);
    }
    if (lane < KP) Bp[(size_t)task * KP + lane] = c;
}

// ---- kernel 3a: within-group running partials + group polys (both directions)
__global__ void k_group_partial(const double* __restrict__ Bp,
                                double* __restrict__ sfxIncl, double* __restrict__ prePart,
                                double* __restrict__ gpoly) {
    int lane = threadIdx.x;
    int task = blockIdx.x;                 // (b*2+dir)*NG + g
    int g = task % NG;
    int bd = task / NG;
    int dir = bd & 1, b = bd >> 1;
    double run = (lane == 0) ? 1.0 : 0.0;
    if (dir == 0) {                        // suffix: inclusive within group
        for (int idx = GSZ - 1; idx >= 0; --idx) {
            int m = g * GSZ + idx;
            double bp = (lane < KP) ? Bp[((size_t)b * MBLK + m) * KP + lane] : 0.0;
            run = conv33(bp, run);
            if (lane < KP) sfxIncl[((size_t)b * MBLK + m) * KP + lane] = run;
        }
    } else {                               // prefix: exclusive within group
        for (int idx = 0; idx < GSZ; ++idx) {
            int m = g * GSZ + idx;
            if (lane < KP) prePart[((size_t)b * MBLK + m) * KP + lane] = run;
            double bp = (lane < KP) ? Bp[((size_t)b * MBLK + m) * KP + lane] : 0.0;
            run = conv33(run, bp);
        }
    }
    if (lane < KP) gpoly[(size_t)task * KP + lane] = run;
}

// ---- kernel 3b: scan over the 16 group polys (exclusive carries)
__global__ void k_group_scan(const double* __restrict__ gpoly, double* __restrict__ gcarry) {
    int lane = threadIdx.x;
    int task = blockIdx.x;                 // b*2 + dir
    int dir = task & 1;
    double run = (lane == 0) ? 1.0 : 0.0;
    for (int step = 0; step < NG; ++step) {
        int g = dir ? step : (NG - 1 - step);
        if (lane < KP) gcarry[((size_t)task * NG + g) * KP + lane] = run;
        double gp = (lane < KP) ? gpoly[((size_t)task * NG + g) * KP + lane] : 0.0;
        run = conv33(gp, run);
    }
}

// ---- kernel 3c: per-block checkpoints C (suffix) and P (prefix)
__global__ void k_checkpoints(const double* __restrict__ sfxIncl, const double* __restrict__ prePart,
                              const double* __restrict__ gcarry,
                              double* __restrict__ C, double* __restrict__ P) {
    int lane = threadIdx.x;
    int task = blockIdx.x;                 // (b*2+dir)*MBLK + m
    int m = task % MBLK;
    int bd = task / MBLK;
    int dir = bd & 1, b = bd >> 1;
    int g = m / GSZ;
    if (dir == 0) {
        double a = (lane < KP) ? sfxIncl[((size_t)b * MBLK + m) * KP + lane] : 0.0;
        double cg = (lane < KP) ? gcarry[(((size_t)b * 2 + 0) * NG + g) * KP + lane] : 0.0;
        double out = conv33(a, cg);
        if (lane < KP) C[((size_t)b * (MBLK + 1) + m) * KP + lane] = out;
        if (m == 0 && lane < KP)
            C[((size_t)b * (MBLK + 1) + MBLK) * KP + lane] = (lane == 0) ? 1.0 : 0.0;
    } else {
        double a = (lane < KP) ? gcarry[(((size_t)b * 2 + 1) * NG + g) * KP + lane] : 0.0;
        double pp = (lane < KP) ? prePart[((size_t)b * MBLK + m) * KP + lane] : 0.0;
        double out = conv33(a, pp);
        if (lane < KP) P[((size_t)b * MBLK + m) * KP + lane] = out;
    }
}

// ---- kernel 4: fused per-block: recompute within-block sfx (LDS), sampler tables
//      for all 33 entry states (s=0 wave0, s=1 wave1), marginals (wave2)
__global__ void k_fused(const double* __restrict__ X, const double* __restrict__ C,
                        const double* __restrict__ P, const float* __restrict__ U,
                        float* __restrict__ margw, unsigned* __restrict__ bitsw,
                        int* __restrict__ tablew) {
    __shared__ double sfxL[LBLK + 1][KP];
    int tid = threadIdx.x;
    int wave = tid >> 6, lane = tid & 63;
    int task = blockIdx.x;                 // b*MBLK + m
    int b = task / MBLK, m = task % MBLK;
    const double* xb = X + (size_t)b * NPADC + (size_t)m * LBLK;

    if (wave == 0) {
        double c = (lane < KP) ? C[((size_t)b * (MBLK + 1) + m + 1) * KP + lane] : 0.0;
        if (lane < KP) sfxL[LBLK][lane] = c;
        for (int j = LBLK - 1; j >= 0; --j) {
            double xv = xb[j];
            double up = shfl_up1(c);
            if (lane == 0) up = 0.0;
            c = fma(xv, up, c);
            if (lane < KP) sfxL[j][lane] = c;
        }
    }
    __syncthreads();

    if (wave < 2) {
        int s = wave;
        int r = lane;
        unsigned bw0 = 0, bw1 = 0, bw2 = 0, bw3 = 0;
        const float* us = U + ((size_t)s * NPADC + (size_t)m * LBLK) * BCH + b;
        for (int j = 0; j < LBLK; ++j) {
            double u = (double)us[(size_t)j * BCH];
            double xv = xb[j];
            bool inc = false;
            if (r > 0 && lane < KP) {
                double num = sfxL[j + 1][r - 1];
                double den = sfxL[j][r];
                inc = (u * den < xv * num);
            }
            if (inc) {
                if (j < 32) bw0 |= (1u << j);
                else if (j < 64) bw1 |= (1u << (j - 32));
                else if (j < 96) bw2 |= (1u << (j - 64));
                else bw3 |= (1u << (j - 96));
                --r;
            }
        }
        if (lane < KP) {
            size_t base = ((size_t)(s * BCH + b) * MBLK + m) * KP + lane;
            tablew[base] = r;
            bitsw[base * 4 + 0] = bw0;
            bitsw[base * 4 + 1] = bw1;
            bitsw[base * 4 + 2] = bw2;
            bitsw[base * 4 + 3] = bw3;
        }
    } else {
        double pre = (lane < KP) ? P[((size_t)b * MBLK + m) * KP + lane] : 0.0;
        double invZ = 1.0 / C[((size_t)b * (MBLK + 1)) * KP + KK];
        for (int j = 0; j < LBLK; ++j) {
            double term = (lane < KK) ? pre * sfxL[j + 1][KK - 1 - lane] : 0.0;
            for (int off = 32; off > 0; off >>= 1) term += __shfl_xor(term, off, 64);
            double xv = xb[j];
            if (lane == 0)
                margw[(size_t)b * NPADC + (size_t)m * LBLK + j] = (float)(xv * term * invZ);
            double up = shfl_up1(pre);
            if (lane == 0) up = 0.0;
            pre = fma(xv, up, pre);
        }
    }
}

// ---- kernel 5: compose the per-block transition tables along each (s,b) chain
__global__ void k_compose(const int* __restrict__ tablew, int* __restrict__ rent) {
    __shared__ int tbl[MBLK][KP];
    int sb = blockIdx.x;                   // s*BCH + b
    int tid = threadIdx.x;                 // 64
    const int* src = tablew + (size_t)sb * MBLK * KP;
    for (int idx = tid; idx < MBLK * KP; idx += 64)
        tbl[idx / KP][idx % KP] = src[idx];
    __syncthreads();
    if (tid == 0) {
        int r = KK;
        for (int m = 0; m < MBLK; ++m) {
            rent[(size_t)sb * MBLK + m] = r;
            r = tbl[m][r];
        }
    }
}

// ---- kernel 6: gather realized bits, write symmetric mask
__global__ void k_emit_mask(const unsigned* __restrict__ bitsw, const int* __restrict__ rent,
                            float* __restrict__ outMask) {
    int task = blockIdx.x;                 // sb*MBLK + m
    int j = threadIdx.x;                   // 0..127
    int m = task % MBLK;
    int sb = task / MBLK;
    int t = m * LBLK + j;
    if (t >= TARGETC) return;
    int r0 = rent[(size_t)sb * MBLK + m];
    unsigned w = bitsw[(((size_t)sb * MBLK + m) * KP + r0) * 4 + (j >> 5)];
    float v = (float)((w >> (j & 31)) & 1u);
    int i, jj;
    decode_ij(t, i, jj);
    float* base = outMask + (size_t)sb * NMAXC * NMAXC;
    base[i * NMAXC + jj] = v;
    base[jj * NMAXC + i] = v;
}

// ---- kernel 7: write symmetric marginals
__global__ void k_emit_marg(const float* __restrict__ margw, float* __restrict__ outMarg) {
    int idx = blockIdx.x * blockDim.x + threadIdx.x;
    if (idx >= BCH * TARGETC) return;
    int b = idx / TARGETC, t = idx % TARGETC;
    float v = margw[(size_t)b * NPADC + t];
    int i, j;
    decode_ij(t, i, j);
    outMarg[((size_t)b * NMAXC + i) * NMAXC + j] = v;
    outMarg[((size_t)b * NMAXC + j) * NMAXC + i] = v;
}

extern "C" void kernel_launch(void* const* d_in, const int* in_sizes, int n_in,
                              void* d_out, int out_size, void* d_ws, size_t ws_size,
                              hipStream_t stream) {
    const float* scores = (const float*)d_in[0];
    const float* uniforms = (const float*)d_in[1];

    char* ws = (char*)d_ws;
    size_t off = 0;
    auto alloc = [&](size_t bytes) {
        void* p = ws + off;
        off += (bytes + 255) & ~(size_t)255;
        return p;
    };
    double* X      = (double*)alloc((size_t)BCH * NPADC * 8);
    double* Bp     = (double*)alloc((size_t)BCH * MBLK * KP * 8);
    double* sfxI   = (double*)alloc((size_t)BCH * MBLK * KP * 8);
    double* preP   = (double*)alloc((size_t)BCH * MBLK * KP * 8);
    double* gpoly  = (double*)alloc((size_t)BCH * 2 * NG * KP * 8);
    double* gcarry = (double*)alloc((size_t)BCH * 2 * NG * KP * 8);
    double* C      = (double*)alloc((size_t)BCH * (MBLK + 1) * KP * 8);
    double* P      = (double*)alloc((size_t)BCH * MBLK * KP * 8);
    float*  margw  = (float*)alloc((size_t)BCH * NPADC * 4);
    unsigned* bitsw = (unsigned*)alloc((size_t)SS * BCH * MBLK * KP * 4 * 4);
    int* tablew    = (int*)alloc((size_t)SS * BCH * MBLK * KP * 4);
    int* rent      = (int*)alloc((size_t)SS * BCH * MBLK * 4);
    if (off > ws_size) return;  // workspace too small (should not happen: ~35 MB)

    hipMemsetAsync(d_out, 0, (size_t)out_size * sizeof(float), stream);

    k_exp_theta<<<(BCH * NPADC + 255) / 256, 256, 0, stream>>>(scores, X);
    k_block_poly<<<BCH * MBLK, 64, 0, stream>>>(X, Bp);
    k_group_partial<<<BCH * 2 * NG, 64, 0, stream>>>(Bp, sfxI, preP, gpoly);
    k_group_scan<<<BCH * 2, 64, 0, stream>>>(gpoly, gcarry);
    k_checkpoints<<<BCH * 2 * MBLK, 64, 0, stream>>>(sfxI, preP, gcarry, C, P);
    k_fused<<<BCH * MBLK, 192, 0, stream>>>(X, C, P, uniforms, margw, bitsw, tablew);
    k_compose<<<SS * BCH, 64, 0, stream>>>(tablew, rent);
    k_emit_mask<<<SS * BCH * MBLK, LBLK, 0, stream>>>(bitsw, rent, (float*)d_out);
    k_emit_marg<<<(BCH * TARGETC + 255) / 256, 256, 0, stream>>>(
        margw, (float*)d_out + (size_t)SS * BCH * NMAXC * NMAXC);
}

// Round 2
// 316.579 us; speedup vs baseline: 1.8811x; 1.8811x over previous
//
#include <hip/hip_runtime.h>

#define KK 32
#define KP 33
#define NMAXC 256
#define BCH 32            // bsz * ENS
#define NPADC 32768
#define TARGETC 32640
#define LSEG 64           // items per segment
#define MSEG 512          // NPADC / LSEG
#define GSZ 32            // segments per group
#define NG 16             // MSEG / GSZ
#define SS 2

#define OFFS(i) ((i)*255 - (i)*((i)-1)/2)

__device__ __forceinline__ void decode_ij(int t, int& oi, int& oj) {
    int ii = (int)((511.0 - sqrt(511.0 * 511.0 - 8.0 * (double)t)) * 0.5);
    if (ii < 0) ii = 0;
    if (ii > 254) ii = 254;
    while (ii < 254 && OFFS(ii + 1) <= t) ++ii;
    while (ii > 0 && OFFS(ii) > t) --ii;
    oi = ii;
    oj = t - OFFS(ii) + ii + 1;
}

// 33-point truncated polynomial product: out[r] = sum_{j<=r} a[j]*b[r-j], lanes hold coeffs.
// Only lanes 0..32 of a,b are ever read; output lanes >=33 are garbage (unused).
__device__ __forceinline__ double conv33(double a, double b) {
    int lane = threadIdx.x & 63;
    double s0 = 0.0, s1 = 0.0;
#pragma unroll
    for (int j = 0; j < KP; ++j) {
        double aj = __shfl(a, j, 64);
        double bs = __shfl_up(b, j, 64);     // b[lane-j] for lane>=j
        double m = (j <= lane) ? aj : 0.0;
        if (j & 1) s1 = fma(m, bs, s1); else s0 = fma(m, bs, s0);
    }
    return s0 + s1;
}

// ---- kernel 1: x = exp(theta)
__global__ void k_exp_theta(const float* __restrict__ sc, double* __restrict__ X) {
    int idx = blockIdx.x * blockDim.x + threadIdx.x;
    if (idx >= BCH * NPADC) return;
    int b = idx >> 15;
    int t = idx & (NPADC - 1);
    double x = 0.0;
    if (t < TARGETC) {
        int i, j;
        decode_ij(t, i, j);
        double th = (double)sc[(b * NMAXC + i) * NMAXC + j] + (double)sc[(b * NMAXC + j) * NMAXC + i];
        x = exp(th);
    }
    X[idx] = x;
}

// ---- kernel 2: per-segment elementary symmetric polys (64 items)
__global__ void k_block_poly(const double* __restrict__ X, double* __restrict__ Bp) {
    int lane = threadIdx.x;
    int blk = blockIdx.x;                 // b*MSEG + m
    int b = blk / MSEG, m = blk % MSEG;
    double xa = X[(size_t)b * NPADC + (size_t)m * LSEG + lane];
    double c = (lane == 0) ? 1.0 : 0.0;
#pragma unroll
    for (int j = 0; j < LSEG; ++j) {
        double xj = __shfl(xa, j, 64);
        double up = __shfl_up(c, 1, 64);
        if (lane == 0) up = 0.0;
        c = fma(xj, up, c);
    }
    if (lane < KP) Bp[(size_t)blk * KP + lane] = c;
}

// ---- kernel 3a: suffix-inclusive within group + group polys
__global__ void k_group_partial(const double* __restrict__ Bp,
                                double* __restrict__ sfxI, double* __restrict__ gpoly) {
    int lane = threadIdx.x;
    int blk = blockIdx.x;                 // b*NG + g
    int b = blk / NG, g = blk % NG;
    double run = (lane == 0) ? 1.0 : 0.0;
    for (int i = GSZ - 1; i >= 0; --i) {
        int m = g * GSZ + i;
        double bp = (lane < KP) ? Bp[((size_t)b * MSEG + m) * KP + lane] : 0.0;
        run = conv33(bp, run);
        if (lane < KP) sfxI[((size_t)b * MSEG + m) * KP + lane] = run;
    }
    if (lane < KP) gpoly[(size_t)blk * KP + lane] = run;
}

// ---- kernel 3b: suffix scan over group polys (exclusive carries)
__global__ void k_group_scan(const double* __restrict__ gpoly, double* __restrict__ gcarry) {
    int lane = threadIdx.x;
    int b = blockIdx.x;
    double run = (lane == 0) ? 1.0 : 0.0;
    for (int g = NG - 1; g >= 0; --g) {
        if (lane < KP) gcarry[((size_t)b * NG + g) * KP + lane] = run;
        double gp = (lane < KP) ? gpoly[((size_t)b * NG + g) * KP + lane] : 0.0;
        run = conv33(gp, run);
    }
}

// ---- kernel 3c: per-segment suffix checkpoints Cc[b][m] = poly of items >= m*64
__global__ void k_checkpoints(const double* __restrict__ sfxI, const double* __restrict__ gcarry,
                              double* __restrict__ Cc) {
    int lane = threadIdx.x;
    int blk = blockIdx.x;                 // b*MSEG + m
    int b = blk / MSEG, m = blk % MSEG;
    double a = (lane < KP) ? sfxI[(size_t)blk * KP + lane] : 0.0;
    double cg = (lane < KP) ? gcarry[((size_t)b * NG + m / GSZ) * KP + lane] : 0.0;
    double out = conv33(a, cg);
    if (lane < KP) Cc[((size_t)b * (MSEG + 1) + m) * KP + lane] = out;
    if (m == 0 && lane < KP)
        Cc[((size_t)b * (MSEG + 1) + MSEG) * KP + lane] = (lane == 0) ? 1.0 : 0.0;
}

// ---- kernel 4: backward sfx sweep fused with sampling for both s:
//      per item: ballot of inc over all 33 states + exit-state table compose.
__global__ void k_backward(const double* __restrict__ X, const double* __restrict__ Cc,
                           const float* __restrict__ U,
                           unsigned long long* __restrict__ masks, int* __restrict__ tab) {
    int lane = threadIdx.x;
    int blk = blockIdx.x;                 // m*BCH + b (b fastest: L2 reuse of U lines)
    int b = blk & (BCH - 1), m = blk >> 5;
    double xa = X[(size_t)b * NPADC + (size_t)m * LSEG + lane];
    float u0 = U[((size_t)0 * NPADC + (size_t)m * LSEG + lane) * BCH + b];
    float u1 = U[((size_t)1 * NPADC + (size_t)m * LSEG + lane) * BCH + b];
    double c = (lane < KP) ? Cc[((size_t)b * (MSEG + 1) + m + 1) * KP + lane] : 0.0;
    int S0 = lane, S1 = lane;
    unsigned long long mk0 = 0, mk1 = 0;
#pragma unroll
    for (int j = LSEG - 1; j >= 0; --j) {
        double xj = __shfl(xa, j, 64);
        double up = __shfl_up(c, 1, 64);
        if (lane == 0) up = 0.0;
        double cn = fma(xj, up, c);       // sfx[j][lane]
        double ud0 = (double)__shfl(u0, j, 64);
        double ud1 = (double)__shfl(u1, j, 64);
        double rhs = xj * up;             // x_j * sfx[j+1][lane-1]
        bool i0 = (lane > 0) && (ud0 * cn < rhs);
        bool i1 = (lane > 0) && (ud1 * cn < rhs);
        unsigned long long b0 = __ballot(i0);
        unsigned long long b1 = __ballot(i1);
        if (lane == j) { mk0 = b0; mk1 = b1; }
        int t0 = __shfl_up(S0, 1, 64);
        int t1 = __shfl_up(S1, 1, 64);
        if (i0) S0 = t0;
        if (i1) S1 = t1;
        c = cn;
    }
    masks[((size_t)(0 * BCH + b) * MSEG + m) * LSEG + lane] = mk0;
    masks[((size_t)(1 * BCH + b) * MSEG + m) * LSEG + lane] = mk1;
    if (lane < KP) {
        tab[((size_t)(0 * BCH + b) * MSEG + m) * KP + lane] = S0;
        tab[((size_t)(1 * BCH + b) * MSEG + m) * KP + lane] = S1;
    }
}

// ---- kernel 5: hierarchical compose of per-segment tables -> per-segment entry states
__global__ void k_compose(const int* __restrict__ tab, int* __restrict__ rent) {
    __shared__ int tl[MSEG * KP];         // 67.6 KB
    __shared__ int gtab[16 * KP];
    __shared__ int gent[16];
    int sb = blockIdx.x;                  // s*BCH + b
    int tid = threadIdx.x;                // 1024
    const int* src = tab + (size_t)sb * MSEG * KP;
    for (int i = tid; i < MSEG * KP; i += 1024) tl[i] = src[i];
    __syncthreads();
    int w = tid >> 6, lane = tid & 63;
    int T = lane;                         // identity
    for (int i = 0; i < 32; ++i) {
        int seg = w * 32 + i;
        int tv = (lane < KP) ? tl[seg * KP + lane] : 0;
        T = __shfl(tv, T, 64);            // T = tab_seg[T]
    }
    if (lane < KP) gtab[w * KP + lane] = T;
    __syncthreads();
    if (tid == 0) {
        int r = KK;
        for (int g = 0; g < 16; ++g) { gent[g] = r; r = gtab[g * KP + r]; }
    }
    __syncthreads();
    int r = gent[w];
    for (int i = 0; i < 32; ++i) {
        int seg = w * 32 + i;
        if (lane == 0) rent[(size_t)sb * MSEG + seg] = r;
        r = tl[seg * KP + r];             // uniform broadcast read
    }
}

// ---- kernel 6: replay ballot masks along realized path, emit symmetric mask
__global__ void k_emit_mask(const unsigned long long* __restrict__ masks,
                            const int* __restrict__ rent, float* __restrict__ outMask) {
    int lane = threadIdx.x;
    int blk = blockIdx.x;                 // sb*MSEG + m
    int sb = blk / MSEG, m = blk % MSEG;
    unsigned long long mv = masks[(size_t)blk * LSEG + lane];
    unsigned mlo = (unsigned)mv, mhi = (unsigned)(mv >> 32);
    int r = rent[(size_t)sb * MSEG + m];  // wave-uniform
    int mybit = 0;
#pragma unroll
    for (int j = 0; j < LSEG; ++j) {
        unsigned l = __shfl(mlo, j, 64);
        unsigned h = __shfl(mhi, j, 64);
        unsigned long long mj = ((unsigned long long)h << 32) | l;
        int inc = (int)((mj >> r) & 1ull);
        if (lane == j) mybit = inc;
        r -= inc;
    }
    int t = m * LSEG + lane;
    if (t < TARGETC) {
        int i, jj;
        decode_ij(t, i, jj);
        float v = (float)mybit;
        float* base = outMask + (size_t)sb * NMAXC * NMAXC;
        base[i * NMAXC + jj] = v;
        base[jj * NMAXC + i] = v;
    }
}

// ---- kernel 7: marginals by deflation: f_k = e_k - x*f_{k-1}; p = x*f_{K-1}/Z
__global__ void k_marg(const double* __restrict__ X, const double* __restrict__ Cc,
                       float* __restrict__ outMarg) {
    __shared__ double e[KP];
    int b = blockIdx.y;
    int t = blockIdx.x * 256 + threadIdx.x;
    if (threadIdx.x < KP) e[threadIdx.x] = Cc[(size_t)b * (MSEG + 1) * KP + threadIdx.x];
    __syncthreads();
    if (t >= TARGETC) return;
    double x = X[(size_t)b * NPADC + t];
    double f = 1.0;
#pragma unroll
    for (int k = 1; k < KK; ++k) f = fma(-x, f, e[k]);
    double p = x * f / e[KK];
    int i, j;
    decode_ij(t, i, j);
    float v = (float)p;
    outMarg[((size_t)b * NMAXC + i) * NMAXC + j] = v;
    outMarg[((size_t)b * NMAXC + j) * NMAXC + i] = v;
}

extern "C" void kernel_launch(void* const* d_in, const int* in_sizes, int n_in,
                              void* d_out, int out_size, void* d_ws, size_t ws_size,
                              hipStream_t stream) {
    const float* scores = (const float*)d_in[0];
    const float* uniforms = (const float*)d_in[1];

    char* ws = (char*)d_ws;
    size_t off = 0;
    auto alloc = [&](size_t bytes) {
        void* p = ws + off;
        off += (bytes + 255) & ~(size_t)255;
        return p;
    };
    double* X      = (double*)alloc((size_t)BCH * NPADC * 8);
    double* Bp     = (double*)alloc((size_t)BCH * MSEG * KP * 8);
    double* sfxI   = (double*)alloc((size_t)BCH * MSEG * KP * 8);
    double* gpoly  = (double*)alloc((size_t)BCH * NG * KP * 8);
    double* gcarry = (double*)alloc((size_t)BCH * NG * KP * 8);
    double* Cc     = (double*)alloc((size_t)BCH * (MSEG + 1) * KP * 8);
    unsigned long long* masks = (unsigned long long*)alloc((size_t)SS * BCH * MSEG * LSEG * 8);
    int* tab       = (int*)alloc((size_t)SS * BCH * MSEG * KP * 4);
    int* rent      = (int*)alloc((size_t)SS * BCH * MSEG * 4);
    if (off > ws_size) return;            // ~43 MB

    hipMemsetAsync(d_out, 0, (size_t)out_size * sizeof(float), stream);

    k_exp_theta<<<(BCH * NPADC + 255) / 256, 256, 0, stream>>>(scores, X);
    k_block_poly<<<BCH * MSEG, 64, 0, stream>>>(X, Bp);
    k_group_partial<<<BCH * NG, 64, 0, stream>>>(Bp, sfxI, gpoly);
    k_group_scan<<<BCH, 64, 0, stream>>>(gpoly, gcarry);
    k_checkpoints<<<BCH * MSEG, 64, 0, stream>>>(sfxI, gcarry, Cc);
    k_backward<<<BCH * MSEG, 64, 0, stream>>>(X, Cc, uniforms, masks, tab);
    k_compose<<<SS * BCH, 1024, 0, stream>>>(tab, rent);
    k_emit_mask<<<SS * BCH * MSEG, 64, 0, stream>>>(masks, rent, (float*)d_out);
    k_marg<<<dim3(128, BCH), 256, 0, stream>>>(
        X, Cc, (float*)d_out + (size_t)SS * BCH * NMAXC * NMAXC);
}